// Round 1
// baseline (4437.894 us; speedup 1.0000x reference)
//
#include <hip/hip_runtime.h>
#include <cstdint>

#define B_IMG 32
#define N_PRI 24564
#define N_CLS 81
#define N_FG  80
#define PRE   200
#define MAXD  100
#define NBINS 1024
#define CANDS 512
#define SNAP_ULPS 2
#define SMX_TB 128

#define SCORE_THR_F 0.01f
#define NMS_THR_D   0.45
#define CENTER_VAR_D 0.1
#define SIZE_VAR_D   0.2

// ---------------- Stage A: decode boxes (f64) ----------------
__global__ void decode_kernel(const float* __restrict__ bbox,
                              const float* __restrict__ priors,
                              double* __restrict__ boxes) {
  int n = blockIdx.x * blockDim.x + threadIdx.x;
  int b = blockIdx.y;
  if (n >= N_PRI) return;
  float4 loc = ((const float4*)bbox)[(size_t)b * N_PRI + n];
  float4 pr  = ((const float4*)priors)[n];
  double cx = ((double)loc.x * CENTER_VAR_D) * (double)pr.z + (double)pr.x;
  double cy = ((double)loc.y * CENTER_VAR_D) * (double)pr.w + (double)pr.y;
  double w  = exp((double)loc.z * SIZE_VAR_D) * (double)pr.z;
  double h  = exp((double)loc.w * SIZE_VAR_D) * (double)pr.w;
  double* o = boxes + ((size_t)b * N_PRI + n) * 4;
  double2 lo, hi;
  lo.x = cx - w * 0.5; lo.y = cy - h * 0.5;
  hi.x = cx + w * 0.5; hi.y = cy + h * 0.5;
  ((double2*)o)[0] = lo;
  ((double2*)o)[1] = hi;
}

// ---------------- Stage B: f64 softmax -> f32 scores, same-prior ulp-snap, transposed ----------------
// v2: LDS-staged rows (coalesced float4 global reads, single pass over logits),
//     ps[] lives in LDS (in-place over the staged row) instead of scratch.
//     Numerics are bit-identical to v1 (same f64 ops, same order, same snap sequence).
__global__ __launch_bounds__(SMX_TB) void softmax_fg_kernel(
    const float* __restrict__ logits, float* __restrict__ fgT, int b0) {
  __shared__ float S[SMX_TB * N_CLS];   // 128*81*4 = 41472 B; [t][81]: bank=(17t+c)%32, conflict-free
  int t = threadIdx.x;
  int rows0 = blockIdx.x * SMX_TB;
  int lb = blockIdx.y;
  int b = b0 + lb;
  int nrows = N_PRI - rows0; if (nrows > SMX_TB) nrows = SMX_TB;
  int nfl = nrows * N_CLS;

  // cooperative staging: block window is 16B-aligned (128*81*4 % 16 == 0, b*N_PRI*81*4 % 16 == 0)
  const float* srcf = logits + ((size_t)b * N_PRI + rows0) * N_CLS;
  const float4* src4 = (const float4*)srcf;
  float4* S4 = (float4*)S;
  int nv4 = nfl >> 2;                 // nfl divisible by 4 for nrows in {128,116}
  for (int i = t; i < nv4; i += SMX_TB) S4[i] = src4[i];
  for (int i = (nv4 << 2) + t; i < nfl; i += SMX_TB) S[i] = srcf[i];  // safety tail (empty here)
  __syncthreads();

  int n = rows0 + t;
  if (n < N_PRI) {
    float* row = S + t * N_CLS;
    float m = row[0];
#pragma unroll
    for (int j = 1; j < N_CLS; ++j) m = fmaxf(m, row[j]);
    double dm = (double)m;
    double d = 0.0;
#pragma unroll
    for (int j = 0; j < N_CLS; ++j) d += exp((double)row[j] - dm);

    // in-place: row[c-1] <- ps for class c. Slot c-1 was already consumed (read at iter c-1).
    for (int c = 1; c < N_CLS; ++c) {
      float p = (float)(exp((double)row[c] - dm) / d);   // correctly-rounded-f32 of f64 value
      row[c - 1] = (p > SCORE_THR_F) ? p : 0.0f;
    }
    // Snap near-tied (<= SNAP_ULPS) cross-class scores of this prior to exact equality,
    // earliest class wins -> downstream stable index tie-break mimics np-f32 tie collapse.
    for (int c2 = 1; c2 < N_FG; ++c2) {
      float v2 = row[c2];
      if (v2 <= 0.0f) continue;
      int u2 = (int)__float_as_uint(v2);
      for (int c1 = 0; c1 < c2; ++c1) {
        float v1 = row[c1];
        if (v1 <= 0.0f) continue;
        int du = (int)__float_as_uint(v1) - u2;
        if (du <= SNAP_ULPS && du >= -SNAP_ULPS) { row[c2] = v1; break; }
      }
    }
    float* outb = fgT + (size_t)lb * N_FG * N_PRI + n;
    for (int c = 0; c < N_FG; ++c)
      outb[(size_t)c * N_PRI] = row[c];
  }
}

// ---------------- Stage C: exact top-200 per (b, class), packed u64 keys ----------------
__global__ __launch_bounds__(256) void topk_kernel(const float* __restrict__ fgT,
                                                   float* __restrict__ topk_sc,
                                                   int* __restrict__ topk_idx, int b0) {
  __shared__ unsigned int hist[NBINS];
  __shared__ unsigned long long cand[CANDS];
  __shared__ unsigned int part[256];
  __shared__ int s_cut;
  __shared__ unsigned int s_cnt;
  int t = threadIdx.x;
  int c = blockIdx.x;
  int lb = blockIdx.y;
  int gb = b0 + lb;
  const float* src = fgT + ((size_t)lb * N_FG + c) * N_PRI;

  for (int i = t; i < NBINS; i += 256) hist[i] = 0;
  if (t == 0) s_cnt = 0;
  __syncthreads();

  for (int i = t; i < N_PRI; i += 256) {
    float v = src[i];
    if (v > 0.0f) atomicAdd(&hist[__float_as_uint(v) >> 21], 1u);
  }
  __syncthreads();

  unsigned s = 0;
  for (int j = 0; j < 4; ++j) s += hist[t * 4 + j];
  part[t] = s;
  __syncthreads();

  if (t == 0) {
    unsigned acc = 0; int cut = -1;
    for (int tb = 255; tb >= 0 && cut < 0; --tb) {
      unsigned pa = part[tb];
      if (acc + pa >= PRE) {
        for (int bin = tb * 4 + 3; bin >= tb * 4; --bin) {
          acc += hist[bin];
          if (acc >= PRE) { cut = bin; break; }
        }
      } else acc += pa;
    }
    s_cut = (cut < 0) ? 0 : cut;
  }
  __syncthreads();
  int cut = s_cut;

  for (int i = t; i < N_PRI; i += 256) {
    float v = src[i];
    if (v > 0.0f) {
      unsigned u = __float_as_uint(v);
      if ((int)(u >> 21) >= cut) {
        unsigned pos = atomicAdd(&s_cnt, 1u);
        if (pos < CANDS)
          cand[pos] = ((unsigned long long)u << 32) |
                      (unsigned long long)(0xFFFFFFFFu - (unsigned)i);
      }
    }
  }
  __syncthreads();
  unsigned cnt = s_cnt; if (cnt > CANDS) cnt = CANDS;
  for (int i = t; i < CANDS; i += 256)
    if ((unsigned)i >= cnt) cand[i] = 0ull;
  __syncthreads();

  // bitonic sort descending: value desc, then smaller index first
  for (int k = 2; k <= CANDS; k <<= 1) {
    for (int j = k >> 1; j > 0; j >>= 1) {
      for (int i = t; i < CANDS; i += 256) {
        int ixj = i ^ j;
        if (ixj > i) {
          unsigned long long a = cand[i], bb = cand[ixj];
          bool up = ((i & k) == 0);
          if (up ? (a < bb) : (a > bb)) { cand[i] = bb; cand[ixj] = a; }
        }
      }
      __syncthreads();
    }
  }

  if (t < PRE) {
    unsigned long long key = cand[t];
    float v = __uint_as_float((unsigned)(key >> 32));
    unsigned idx = 0xFFFFFFFFu - (unsigned)(key & 0xFFFFFFFFull);
    if (idx >= N_PRI) idx = 0;
    size_t o = ((size_t)gb * N_FG + c) * PRE + t;
    topk_sc[o] = v;
    topk_idx[o] = (int)idx;
  }
}

// ---------------- Stage D: greedy NMS per (b, class), one wave, f64 IoU ----------------
__global__ __launch_bounds__(64) void nms_kernel(const float* __restrict__ topk_sc,
                                                 const int* __restrict__ topk_idx,
                                                 const double* __restrict__ boxes,
                                                 float* __restrict__ cls_sc) {
  __shared__ double bx[PRE][4];
  __shared__ double ar[PRE];
  __shared__ float sc[PRE];
  __shared__ unsigned char supp[PRE];
  int t = threadIdx.x;
  int c = blockIdx.x, b = blockIdx.y;
  size_t base = ((size_t)b * N_FG + c) * PRE;

  for (int k = t; k < PRE; k += 64) {
    int idx = topk_idx[base + k];
    const double* bp = boxes + ((size_t)b * N_PRI + idx) * 4;
    double x1 = bp[0], y1 = bp[1], x2 = bp[2], y2 = bp[3];
    bx[k][0] = x1; bx[k][1] = y1; bx[k][2] = x2; bx[k][3] = y2;
    ar[k] = fmax(x2 - x1, 0.0) * fmax(y2 - y1, 0.0);
    sc[k] = topk_sc[base + k];
    supp[k] = 0;
  }
  __syncthreads();

  double mybx[4][4]; double mya[4]; bool mykeep[4];
  for (int r = 0; r < 4; ++r) {
    int k = t + r * 64;
    mykeep[r] = false;
    if (k < PRE) {
      mybx[r][0] = bx[k][0]; mybx[r][1] = bx[k][1];
      mybx[r][2] = bx[k][2]; mybx[r][3] = bx[k][3];
      mya[r] = ar[k];
    }
  }

  for (int i = 0; i < PRE; ++i) {
    bool keep_i = (sc[i] > 0.0f) && (supp[i] == 0);
    if ((i & 63) == t) mykeep[i >> 6] = keep_i;
    if (keep_i) {
      double x1 = bx[i][0], y1 = bx[i][1], x2 = bx[i][2], y2 = bx[i][3];
      double ai = ar[i];
      for (int r = 0; r < 4; ++r) {
        int k = t + r * 64;
        if (k < PRE && k > i) {
          double xx1 = fmax(x1, mybx[r][0]), yy1 = fmax(y1, mybx[r][1]);
          double xx2 = fmin(x2, mybx[r][2]), yy2 = fmin(y2, mybx[r][3]);
          double inter = fmax(xx2 - xx1, 0.0) * fmax(yy2 - yy1, 0.0);
          double uni = fmax(ai + mya[r] - inter, 1e-9);
          if (inter / uni > NMS_THR_D) supp[k] = 1;
        }
      }
    }
    __syncthreads();
  }

  for (int r = 0; r < 4; ++r) {
    int k = t + r * 64;
    if (k < PRE) cls_sc[base + k] = mykeep[r] ? sc[k] : 0.0f;
  }
}

// ---------------- Stage E: per-image top-100 + gather outputs ----------------
__global__ __launch_bounds__(256) void final_kernel(const float* __restrict__ cls_sc,
                                                    const int* __restrict__ topk_idx,
                                                    const double* __restrict__ boxes,
                                                    float* __restrict__ out) {
  __shared__ unsigned int hist[NBINS];
  __shared__ unsigned long long cand[CANDS];
  __shared__ unsigned int part[256];
  __shared__ int s_cut;
  __shared__ unsigned int s_cnt;
  const int M = N_FG * PRE;  // 16000
  int t = threadIdx.x, b = blockIdx.x;
  const float* src = cls_sc + (size_t)b * M;

  for (int i = t; i < NBINS; i += 256) hist[i] = 0;
  if (t == 0) s_cnt = 0;
  __syncthreads();

  for (int i = t; i < M; i += 256) {
    float v = src[i];
    if (v > 0.0f) atomicAdd(&hist[__float_as_uint(v) >> 21], 1u);
  }
  __syncthreads();

  unsigned s = 0;
  for (int j = 0; j < 4; ++j) s += hist[t * 4 + j];
  part[t] = s;
  __syncthreads();

  if (t == 0) {
    unsigned acc = 0; int cut = -1;
    for (int tb = 255; tb >= 0 && cut < 0; --tb) {
      unsigned pa = part[tb];
      if (acc + pa >= MAXD) {
        for (int bin = tb * 4 + 3; bin >= tb * 4; --bin) {
          acc += hist[bin];
          if (acc >= MAXD) { cut = bin; break; }
        }
      } else acc += pa;
    }
    s_cut = (cut < 0) ? 0 : cut;
  }
  __syncthreads();
  int cut = s_cut;

  for (int i = t; i < M; i += 256) {
    float v = src[i];
    if (v > 0.0f) {
      unsigned u = __float_as_uint(v);
      if ((int)(u >> 21) >= cut) {
        unsigned pos = atomicAdd(&s_cnt, 1u);
        if (pos < CANDS)
          cand[pos] = ((unsigned long long)u << 32) |
                      (unsigned long long)(0xFFFFFFFFu - (unsigned)i);
      }
    }
  }
  __syncthreads();
  unsigned cnt = s_cnt; if (cnt > CANDS) cnt = CANDS;
  for (int i = t; i < CANDS; i += 256)
    if ((unsigned)i >= cnt) cand[i] = 0ull;
  __syncthreads();

  for (int k = 2; k <= CANDS; k <<= 1) {
    for (int j = k >> 1; j > 0; j >>= 1) {
      for (int i = t; i < CANDS; i += 256) {
        int ixj = i ^ j;
        if (ixj > i) {
          unsigned long long a = cand[i], bb = cand[ixj];
          bool up = ((i & k) == 0);
          if (up ? (a < bb) : (a > bb)) { cand[i] = bb; cand[ixj] = a; }
        }
      }
      __syncthreads();
    }
  }

  if (t < MAXD) {
    unsigned long long key = cand[t];
    float v = __uint_as_float((unsigned)(key >> 32));
    unsigned f = 0xFFFFFFFFu - (unsigned)(key & 0xFFFFFFFFull);
    if (f >= (unsigned)M) f = 0;
    int c = (int)(f / PRE), k = (int)(f % PRE);
    int idx = topk_idx[((size_t)b * N_FG + c) * PRE + k];
    if (idx < 0 || idx >= N_PRI) idx = 0;
    const double* bp = boxes + ((size_t)b * N_PRI + idx) * 4;
    float4 bb = make_float4((float)bp[0], (float)bp[1], (float)bp[2], (float)bp[3]);
    ((float4*)out)[b * MAXD + t] = bb;                              // det_bx
    out[B_IMG * MAXD * 4 + b * MAXD + t] = v;                       // det_sc
    out[B_IMG * MAXD * 5 + b * MAXD + t] = (float)(c + 1);          // det_lb (as float)
  }
}

extern "C" void kernel_launch(void* const* d_in, const int* in_sizes, int n_in,
                              void* d_out, int out_size, void* d_ws, size_t ws_size,
                              hipStream_t stream) {
  const float* cls_logits = (const float*)d_in[0];
  const float* bbox_pred  = (const float*)d_in[1];
  const float* priors     = (const float*)d_in[2];
  float* out = (float*)d_out;

  double* boxes   = (double*)d_ws;                                    // B*N*4 f64
  float* topk_sc  = (float*)(boxes + (size_t)B_IMG * N_PRI * 4);      // B*80*200 f32
  int*   topk_idx = (int*)(topk_sc + (size_t)B_IMG * N_FG * PRE);     // B*80*200 i32
  float* cls_sc   = (float*)(topk_idx + (size_t)B_IMG * N_FG * PRE);  // B*80*200 f32
  float* fgT      = cls_sc + (size_t)B_IMG * N_FG * PRE;              // chunkB*80*N f32

  size_t persist_bytes = (size_t)((char*)fgT - (char*)d_ws);
  size_t per_b = (size_t)N_FG * N_PRI * sizeof(float);
  int chunkB = 1;
  if (ws_size > persist_bytes) {
    size_t cb = (ws_size - persist_bytes) / per_b;
    chunkB = (cb >= (size_t)B_IMG) ? B_IMG : (cb < 1 ? 1 : (int)cb);
  }

  decode_kernel<<<dim3((N_PRI + 255) / 256, B_IMG), 256, 0, stream>>>(
      bbox_pred, priors, boxes);

  for (int b0 = 0; b0 < B_IMG; b0 += chunkB) {
    int nb = (B_IMG - b0) < chunkB ? (B_IMG - b0) : chunkB;
    softmax_fg_kernel<<<dim3((N_PRI + SMX_TB - 1) / SMX_TB, nb), SMX_TB, 0, stream>>>(
        cls_logits, fgT, b0);
    topk_kernel<<<dim3(N_FG, nb), 256, 0, stream>>>(
        fgT, topk_sc, topk_idx, b0);
  }

  nms_kernel<<<dim3(N_FG, B_IMG), 64, 0, stream>>>(
      topk_sc, topk_idx, boxes, cls_sc);

  final_kernel<<<B_IMG, 256, 0, stream>>>(
      cls_sc, topk_idx, boxes, out);
}

// Round 3
// 2317.487 us; speedup vs baseline: 1.9150x; 1.9150x over previous
//
#include <hip/hip_runtime.h>
#include <cstdint>

#define B_IMG 32
#define N_PRI 24564
#define N_CLS 81
#define N_FG  80
#define PRE   200
#define MAXD  100
#define NBINS 1024
#define CANDS 512
#define SNAP_ULPS 2
#define SMX_ROWS 16   // rows per 1-wave block, 4 lanes per row

#define SCORE_THR_F 0.01f
#define NMS_THR_D   0.45
#define CENTER_VAR_D 0.1
#define SIZE_VAR_D   0.2

// ---------------- Stage A: decode boxes (f64) ----------------
__global__ void decode_kernel(const float* __restrict__ bbox,
                              const float* __restrict__ priors,
                              double* __restrict__ boxes) {
  int n = blockIdx.x * blockDim.x + threadIdx.x;
  int b = blockIdx.y;
  if (n >= N_PRI) return;
  float4 loc = ((const float4*)bbox)[(size_t)b * N_PRI + n];
  float4 pr  = ((const float4*)priors)[n];
  double cx = ((double)loc.x * CENTER_VAR_D) * (double)pr.z + (double)pr.x;
  double cy = ((double)loc.y * CENTER_VAR_D) * (double)pr.w + (double)pr.y;
  double w  = exp((double)loc.z * SIZE_VAR_D) * (double)pr.z;
  double h  = exp((double)loc.w * SIZE_VAR_D) * (double)pr.w;
  double* o = boxes + ((size_t)b * N_PRI + n) * 4;
  double2 lo, hi;
  lo.x = cx - w * 0.5; lo.y = cy - h * 0.5;
  hi.x = cx + w * 0.5; hi.y = cy + h * 0.5;
  ((double2*)o)[0] = lo;
  ((double2*)o)[1] = hi;
}

// ---------------- Stage B: f64 softmax -> f32 scores, same-prior ulp-snap, transposed ----------------
// v3: 4 lanes per row (classes strided mod 4), exps computed ONCE into LDS f64 cache and
//     reused for the ps pass; ordered f64 reduction read back index-ascending (bit-exact
//     vs v1/v2); snap kept serial-in-c2 with the first-match scan parallelized over the
//     4 lanes (min matching c1 == serial first match, reads always see current state).
//     1-wave blocks, 10.4 KB LDS -> ~15 waves/CU (was 6).
__global__ __launch_bounds__(64) void softmax_fg_kernel(
    const float* __restrict__ logits, float* __restrict__ fgT, int b0) {
  __shared__ char raw[SMX_ROWS * N_CLS * 8];
  double* E = (double*)raw;            // E[r*81+c] : exp(l_c - m) in f64
  float*  F = (float*)raw;             // F[(r*81+c)*2] : ps f32 in low word of slot c
  int t = threadIdx.x;                 // 0..63
  int j = t & 3;                       // lane within 4-lane row group
  int r = t >> 2;                      // row within block, 0..15
  int lb = blockIdx.y;
  int b  = b0 + lb;
  int n  = blockIdx.x * SMX_ROWS + r;
  bool act = (n < N_PRI);

  // load this lane's strided classes (c = j, j+4, ...) and local max
  float lv[21];
  float m = -__builtin_huge_valf();
  if (act) {
    const float* row = logits + ((size_t)b * N_PRI + n) * N_CLS;
#pragma unroll
    for (int k = 0; k < 21; ++k) {
      int c = j + 4 * k;
      if (c < N_CLS) { lv[k] = row[c]; m = fmaxf(m, lv[k]); }
    }
  }
  // group max (fmax is associative/commutative; no NaNs) -> same m as serial scan
  m = fmaxf(m, __shfl_xor(m, 1, 64));
  m = fmaxf(m, __shfl_xor(m, 2, 64));
  double dm = (double)m;

  // independent exps -> LDS (no loop-carried deps; pipelines fully)
  if (act) {
#pragma unroll
    for (int k = 0; k < 21; ++k) {
      int c = j + 4 * k;
      if (c < N_CLS) E[r * N_CLS + c] = exp((double)lv[k] - dm);
    }
  }
  __syncthreads();

  // ordered reduction, identical addend sequence to v1/v2 (bit-exact d)
  double d = 0.0;
  if (act) {
#pragma unroll
    for (int c = 0; c < N_CLS; ++c) d += E[r * N_CLS + c];
  }
  __syncthreads();   // everyone done reading E before low words are overwritten

  // ps: reuse cached exps; p = (float)(e/d) same bits as recomputed path
  if (act) {
#pragma unroll
    for (int k = 0; k < 21; ++k) {
      int c = j + 4 * k;
      if (c >= 1 && c < N_CLS) {
        float p = (float)(E[r * N_CLS + c] / d);
        F[(r * N_CLS + c) * 2] = (p > SCORE_THR_F) ? p : 0.0f;
      }
    }
  }
  __syncthreads();

  // snap near-tied (<= SNAP_ULPS) cross-class scores, earliest class wins.
  // Serial over c2; inner scan split over the 4 lanes; min matching c1 == first match.
  if (act) {
    for (int c2 = 1; c2 < N_FG; ++c2) {
      float v2 = F[(r * N_CLS + c2 + 1) * 2];      // uniform within the 4-lane group
      if (v2 <= 0.0f) continue;
      int u2 = (int)__float_as_uint(v2);
      int found = N_FG;
      for (int c1 = j; c1 < c2; c1 += 4) {
        float v1 = F[(r * N_CLS + c1 + 1) * 2];
        if (v1 <= 0.0f) continue;
        int du = (int)__float_as_uint(v1) - u2;
        if (du <= SNAP_ULPS && du >= -SNAP_ULPS) { found = c1; break; }
      }
      found = min(found, __shfl_xor(found, 1, 64));
      found = min(found, __shfl_xor(found, 2, 64));
      if (found < c2 && j == 0)
        F[(r * N_CLS + c2 + 1) * 2] = F[(r * N_CLS + found + 1) * 2];
    }
  }
  __syncthreads();

  // write transposed fg scores (post-snap values re-read from LDS)
  if (act) {
    float* outb = fgT + (size_t)lb * N_FG * N_PRI + n;
#pragma unroll
    for (int k = 0; k < 21; ++k) {
      int c = j + 4 * k;
      if (c >= 1 && c < N_CLS)
        outb[(size_t)(c - 1) * N_PRI] = F[(r * N_CLS + c) * 2];
    }
  }
}

// ---------------- Stage C: exact top-200 per (b, class), packed u64 keys ----------------
__global__ __launch_bounds__(256) void topk_kernel(const float* __restrict__ fgT,
                                                   float* __restrict__ topk_sc,
                                                   int* __restrict__ topk_idx, int b0) {
  __shared__ unsigned int hist[NBINS];
  __shared__ unsigned long long cand[CANDS];
  __shared__ unsigned int part[256];
  __shared__ int s_cut;
  __shared__ unsigned int s_cnt;
  int t = threadIdx.x;
  int c = blockIdx.x;
  int lb = blockIdx.y;
  int gb = b0 + lb;
  const float* src = fgT + ((size_t)lb * N_FG + c) * N_PRI;

  for (int i = t; i < NBINS; i += 256) hist[i] = 0;
  if (t == 0) s_cnt = 0;
  __syncthreads();

  for (int i = t; i < N_PRI; i += 256) {
    float v = src[i];
    if (v > 0.0f) atomicAdd(&hist[__float_as_uint(v) >> 21], 1u);
  }
  __syncthreads();

  unsigned s = 0;
  for (int j = 0; j < 4; ++j) s += hist[t * 4 + j];
  part[t] = s;
  __syncthreads();

  if (t == 0) {
    unsigned acc = 0; int cut = -1;
    for (int tb = 255; tb >= 0 && cut < 0; --tb) {
      unsigned pa = part[tb];
      if (acc + pa >= PRE) {
        for (int bin = tb * 4 + 3; bin >= tb * 4; --bin) {
          acc += hist[bin];
          if (acc >= PRE) { cut = bin; break; }
        }
      } else acc += pa;
    }
    s_cut = (cut < 0) ? 0 : cut;
  }
  __syncthreads();
  int cut = s_cut;

  for (int i = t; i < N_PRI; i += 256) {
    float v = src[i];
    if (v > 0.0f) {
      unsigned u = __float_as_uint(v);
      if ((int)(u >> 21) >= cut) {
        unsigned pos = atomicAdd(&s_cnt, 1u);
        if (pos < CANDS)
          cand[pos] = ((unsigned long long)u << 32) |
                      (unsigned long long)(0xFFFFFFFFu - (unsigned)i);
      }
    }
  }
  __syncthreads();
  unsigned cnt = s_cnt; if (cnt > CANDS) cnt = CANDS;
  for (int i = t; i < CANDS; i += 256)
    if ((unsigned)i >= cnt) cand[i] = 0ull;
  __syncthreads();

  // bitonic sort descending: value desc, then smaller index first
  for (int k = 2; k <= CANDS; k <<= 1) {
    for (int j = k >> 1; j > 0; j >>= 1) {
      for (int i = t; i < CANDS; i += 256) {
        int ixj = i ^ j;
        if (ixj > i) {
          unsigned long long a = cand[i], bb = cand[ixj];
          bool up = ((i & k) == 0);
          if (up ? (a < bb) : (a > bb)) { cand[i] = bb; cand[ixj] = a; }
        }
      }
      __syncthreads();
    }
  }

  if (t < PRE) {
    unsigned long long key = cand[t];
    float v = __uint_as_float((unsigned)(key >> 32));
    unsigned idx = 0xFFFFFFFFu - (unsigned)(key & 0xFFFFFFFFull);
    if (idx >= N_PRI) idx = 0;
    size_t o = ((size_t)gb * N_FG + c) * PRE + t;
    topk_sc[o] = v;
    topk_idx[o] = (int)idx;
  }
}

// ---------------- Stage D: greedy NMS per (b, class), one wave, f64 IoU ----------------
__global__ __launch_bounds__(64) void nms_kernel(const float* __restrict__ topk_sc,
                                                 const int* __restrict__ topk_idx,
                                                 const double* __restrict__ boxes,
                                                 float* __restrict__ cls_sc) {
  __shared__ double bx[PRE][4];
  __shared__ double ar[PRE];
  __shared__ float sc[PRE];
  __shared__ unsigned char supp[PRE];
  int t = threadIdx.x;
  int c = blockIdx.x, b = blockIdx.y;
  size_t base = ((size_t)b * N_FG + c) * PRE;

  for (int k = t; k < PRE; k += 64) {
    int idx = topk_idx[base + k];
    const double* bp = boxes + ((size_t)b * N_PRI + idx) * 4;
    double x1 = bp[0], y1 = bp[1], x2 = bp[2], y2 = bp[3];
    bx[k][0] = x1; bx[k][1] = y1; bx[k][2] = x2; bx[k][3] = y2;
    ar[k] = fmax(x2 - x1, 0.0) * fmax(y2 - y1, 0.0);
    sc[k] = topk_sc[base + k];
    supp[k] = 0;
  }
  __syncthreads();

  double mybx[4][4]; double mya[4]; bool mykeep[4];
  for (int r = 0; r < 4; ++r) {
    int k = t + r * 64;
    mykeep[r] = false;
    if (k < PRE) {
      mybx[r][0] = bx[k][0]; mybx[r][1] = bx[k][1];
      mybx[r][2] = bx[k][2]; mybx[r][3] = bx[k][3];
      mya[r] = ar[k];
    }
  }

  for (int i = 0; i < PRE; ++i) {
    bool keep_i = (sc[i] > 0.0f) && (supp[i] == 0);
    if ((i & 63) == t) mykeep[i >> 6] = keep_i;
    if (keep_i) {
      double x1 = bx[i][0], y1 = bx[i][1], x2 = bx[i][2], y2 = bx[i][3];
      double ai = ar[i];
      for (int r = 0; r < 4; ++r) {
        int k = t + r * 64;
        if (k < PRE && k > i) {
          double xx1 = fmax(x1, mybx[r][0]), yy1 = fmax(y1, mybx[r][1]);
          double xx2 = fmin(x2, mybx[r][2]), yy2 = fmin(y2, mybx[r][3]);
          double inter = fmax(xx2 - xx1, 0.0) * fmax(yy2 - yy1, 0.0);
          double uni = fmax(ai + mya[r] - inter, 1e-9);
          if (inter / uni > NMS_THR_D) supp[k] = 1;
        }
      }
    }
    __syncthreads();
  }

  for (int r = 0; r < 4; ++r) {
    int k = t + r * 64;
    if (k < PRE) cls_sc[base + k] = mykeep[r] ? sc[k] : 0.0f;
  }
}

// ---------------- Stage E: per-image top-100 + gather outputs ----------------
__global__ __launch_bounds__(256) void final_kernel(const float* __restrict__ cls_sc,
                                                    const int* __restrict__ topk_idx,
                                                    const double* __restrict__ boxes,
                                                    float* __restrict__ out) {
  __shared__ unsigned int hist[NBINS];
  __shared__ unsigned long long cand[CANDS];
  __shared__ unsigned int part[256];
  __shared__ int s_cut;
  __shared__ unsigned int s_cnt;
  const int M = N_FG * PRE;  // 16000
  int t = threadIdx.x, b = blockIdx.x;
  const float* src = cls_sc + (size_t)b * M;

  for (int i = t; i < NBINS; i += 256) hist[i] = 0;
  if (t == 0) s_cnt = 0;
  __syncthreads();

  for (int i = t; i < M; i += 256) {
    float v = src[i];
    if (v > 0.0f) atomicAdd(&hist[__float_as_uint(v) >> 21], 1u);
  }
  __syncthreads();

  unsigned s = 0;
  for (int j = 0; j < 4; ++j) s += hist[t * 4 + j];
  part[t] = s;
  __syncthreads();

  if (t == 0) {
    unsigned acc = 0; int cut = -1;
    for (int tb = 255; tb >= 0 && cut < 0; --tb) {
      unsigned pa = part[tb];
      if (acc + pa >= MAXD) {
        for (int bin = tb * 4 + 3; bin >= tb * 4; --bin) {
          acc += hist[bin];
          if (acc >= MAXD) { cut = bin; break; }
        }
      } else acc += pa;
    }
    s_cut = (cut < 0) ? 0 : cut;
  }
  __syncthreads();
  int cut = s_cut;

  for (int i = t; i < M; i += 256) {
    float v = src[i];
    if (v > 0.0f) {
      unsigned u = __float_as_uint(v);
      if ((int)(u >> 21) >= cut) {
        unsigned pos = atomicAdd(&s_cnt, 1u);
        if (pos < CANDS)
          cand[pos] = ((unsigned long long)u << 32) |
                      (unsigned long long)(0xFFFFFFFFu - (unsigned)i);
      }
    }
  }
  __syncthreads();
  unsigned cnt = s_cnt; if (cnt > CANDS) cnt = CANDS;
  for (int i = t; i < CANDS; i += 256)
    if ((unsigned)i >= cnt) cand[i] = 0ull;
  __syncthreads();

  for (int k = 2; k <= CANDS; k <<= 1) {
    for (int j = k >> 1; j > 0; j >>= 1) {
      for (int i = t; i < CANDS; i += 256) {
        int ixj = i ^ j;
        if (ixj > i) {
          unsigned long long a = cand[i], bb = cand[ixj];
          bool up = ((i & k) == 0);
          if (up ? (a < bb) : (a > bb)) { cand[i] = bb; cand[ixj] = a; }
        }
      }
      __syncthreads();
    }
  }

  if (t < MAXD) {
    unsigned long long key = cand[t];
    float v = __uint_as_float((unsigned)(key >> 32));
    unsigned f = 0xFFFFFFFFu - (unsigned)(key & 0xFFFFFFFFull);
    if (f >= (unsigned)M) f = 0;
    int c = (int)(f / PRE), k = (int)(f % PRE);
    int idx = topk_idx[((size_t)b * N_FG + c) * PRE + k];
    if (idx < 0 || idx >= N_PRI) idx = 0;
    const double* bp = boxes + ((size_t)b * N_PRI + idx) * 4;
    float4 bb = make_float4((float)bp[0], (float)bp[1], (float)bp[2], (float)bp[3]);
    ((float4*)out)[b * MAXD + t] = bb;                              // det_bx
    out[B_IMG * MAXD * 4 + b * MAXD + t] = v;                       // det_sc
    out[B_IMG * MAXD * 5 + b * MAXD + t] = (float)(c + 1);          // det_lb (as float)
  }
}

extern "C" void kernel_launch(void* const* d_in, const int* in_sizes, int n_in,
                              void* d_out, int out_size, void* d_ws, size_t ws_size,
                              hipStream_t stream) {
  const float* cls_logits = (const float*)d_in[0];
  const float* bbox_pred  = (const float*)d_in[1];
  const float* priors     = (const float*)d_in[2];
  float* out = (float*)d_out;

  double* boxes   = (double*)d_ws;                                    // B*N*4 f64
  float* topk_sc  = (float*)(boxes + (size_t)B_IMG * N_PRI * 4);      // B*80*200 f32
  int*   topk_idx = (int*)(topk_sc + (size_t)B_IMG * N_FG * PRE);     // B*80*200 i32
  float* cls_sc   = (float*)(topk_idx + (size_t)B_IMG * N_FG * PRE);  // B*80*200 f32
  float* fgT      = cls_sc + (size_t)B_IMG * N_FG * PRE;              // chunkB*80*N f32

  size_t persist_bytes = (size_t)((char*)fgT - (char*)d_ws);
  size_t per_b = (size_t)N_FG * N_PRI * sizeof(float);
  int chunkB = 1;
  if (ws_size > persist_bytes) {
    size_t cb = (ws_size - persist_bytes) / per_b;
    chunkB = (cb >= (size_t)B_IMG) ? B_IMG : (cb < 1 ? 1 : (int)cb);
  }

  decode_kernel<<<dim3((N_PRI + 255) / 256, B_IMG), 256, 0, stream>>>(
      bbox_pred, priors, boxes);

  for (int b0 = 0; b0 < B_IMG; b0 += chunkB) {
    int nb = (B_IMG - b0) < chunkB ? (B_IMG - b0) : chunkB;
    softmax_fg_kernel<<<dim3((N_PRI + SMX_ROWS - 1) / SMX_ROWS, nb), 64, 0, stream>>>(
        cls_logits, fgT, b0);
    topk_kernel<<<dim3(N_FG, nb), 256, 0, stream>>>(
        fgT, topk_sc, topk_idx, b0);
  }

  nms_kernel<<<dim3(N_FG, B_IMG), 64, 0, stream>>>(
      topk_sc, topk_idx, boxes, cls_sc);

  final_kernel<<<B_IMG, 256, 0, stream>>>(
      cls_sc, topk_idx, boxes, out);
}

// Round 4
// 1843.038 us; speedup vs baseline: 2.4079x; 1.2574x over previous
//
#include <hip/hip_runtime.h>
#include <cstdint>

#define B_IMG 32
#define N_PRI 24564
#define N_CLS 81
#define N_FG  80
#define PRE   200
#define MAXD  100
#define NBINS 1024
#define CANDS 512
#define SNAP_ULPS 2
#define SMX_ROWS 16   // rows per 1-wave block, 4 lanes per row

#define SCORE_THR_F 0.01f
#define NMS_THR_D   0.45
#define CENTER_VAR_D 0.1
#define SIZE_VAR_D   0.2

// ---------------- Stage A: decode boxes (f64) ----------------
__global__ void decode_kernel(const float* __restrict__ bbox,
                              const float* __restrict__ priors,
                              double* __restrict__ boxes) {
  int n = blockIdx.x * blockDim.x + threadIdx.x;
  int b = blockIdx.y;
  if (n >= N_PRI) return;
  float4 loc = ((const float4*)bbox)[(size_t)b * N_PRI + n];
  float4 pr  = ((const float4*)priors)[n];
  double cx = ((double)loc.x * CENTER_VAR_D) * (double)pr.z + (double)pr.x;
  double cy = ((double)loc.y * CENTER_VAR_D) * (double)pr.w + (double)pr.y;
  double w  = exp((double)loc.z * SIZE_VAR_D) * (double)pr.z;
  double h  = exp((double)loc.w * SIZE_VAR_D) * (double)pr.w;
  double* o = boxes + ((size_t)b * N_PRI + n) * 4;
  double2 lo, hi;
  lo.x = cx - w * 0.5; lo.y = cy - h * 0.5;
  hi.x = cx + w * 0.5; hi.y = cy + h * 0.5;
  ((double2*)o)[0] = lo;
  ((double2*)o)[1] = hi;
}

// Fast inline f64 exp for y <= 0 (no specials; ~1e-14 rel err — 7 orders
// inside the validated 1e-7 selection-robustness margin of this pipeline).
__device__ __forceinline__ double fexp(double y) {
  const double LOG2E = 1.4426950408889634074;
  const double LN2HI = 6.93147180369123816490e-01;
  const double LN2LO = 1.90821492927058770002e-10;
  double kd = rint(y * LOG2E);
  int k = (int)kd;
  if (k < -1020) return 0.0;           // e^y below ~1e-307: contributes nothing
  double r = fma(-kd, LN2HI, y);
  r = fma(-kd, LN2LO, r);
  double p =             2.0876756987868099e-09;   // 1/12!
  p = fma(p, r, 2.5052108385441719e-08);           // 1/11!
  p = fma(p, r, 2.7557319223985891e-07);           // 1/10!
  p = fma(p, r, 2.7557319223985888e-06);           // 1/9!
  p = fma(p, r, 2.4801587301587302e-05);           // 1/8!
  p = fma(p, r, 1.9841269841269841e-04);           // 1/7!
  p = fma(p, r, 1.3888888888888889e-03);           // 1/6!
  p = fma(p, r, 8.3333333333333332e-03);           // 1/5!
  p = fma(p, r, 4.1666666666666664e-02);           // 1/4!
  p = fma(p, r, 1.6666666666666666e-01);           // 1/3!
  p = fma(p, r, 0.5);                              // 1/2!
  p = fma(p, r, 1.0);
  p = fma(p, r, 1.0);
  double s = __longlong_as_double(((long long)(k + 1023)) << 52);
  return p * s;
}

// ---------------- Stage B: f64 softmax -> f32 scores, same-prior ulp-snap, transposed ----------------
// v4: exps kept in REGISTERS (no E array); inline poly exp; 4-lane shfl tree sum
//     (commutative f64 adds -> identical bits across the group); one reciprocal per
//     row instead of 80 divisions; F in class-major LDS layout F[fg*16+r] ->
//     bank=(16j+r)%32 = 2 lanes/bank (conflict-free). Snap semantics unchanged.
__global__ __launch_bounds__(64, 4) void softmax_fg_kernel(
    const float* __restrict__ logits, float* __restrict__ fgT, int b0) {
  __shared__ float F[N_FG * SMX_ROWS];   // F[fg*16 + r], 5120 B
  int t = threadIdx.x;                 // 0..63
  int j = t & 3;                       // lane within 4-lane row group
  int r = t >> 2;                      // row within block, 0..15
  int lb = blockIdx.y;
  int b  = b0 + lb;
  int n  = blockIdx.x * SMX_ROWS + r;
  bool act = (n < N_PRI);

  // load this lane's strided classes (c = j, j+4, ...) and local max
  float lv[21];
  float m = -__builtin_huge_valf();
  if (act) {
    const float* row = logits + ((size_t)b * N_PRI + n) * N_CLS;
#pragma unroll
    for (int k = 0; k < 21; ++k) {
      int c = j + 4 * k;
      if (c < N_CLS) { lv[k] = row[c]; m = fmaxf(m, lv[k]); }
    }
  }
  // group max (fmax assoc/comm, no NaNs) -> same m as serial scan
  m = fmaxf(m, __shfl_xor(m, 1, 64));
  m = fmaxf(m, __shfl_xor(m, 2, 64));
  double dm = (double)m;

  // independent exps -> registers (static indices; no LDS round-trip)
  double ev[21];
  double s = 0.0;
  if (act) {
#pragma unroll
    for (int k = 0; k < 21; ++k) {
      int c = j + 4 * k;
      if (c < N_CLS) { ev[k] = fexp((double)lv[k] - dm); s += ev[k]; }
    }
  }
  // 4-lane tree sum; a+b==b+a bitwise for finite positives -> identical d on all 4 lanes
  s += __shfl_xor(s, 1, 64);
  s += __shfl_xor(s, 2, 64);
  double inv = 1.0 / s;

  // ps: p = (float)(e * (1/d)); threshold; write class-major F
  if (act) {
#pragma unroll
    for (int k = 0; k < 21; ++k) {
      int c = j + 4 * k;
      if (c >= 1 && c < N_CLS) {
        float p = (float)(ev[k] * inv);
        F[(c - 1) * SMX_ROWS + r] = (p > SCORE_THR_F) ? p : 0.0f;
      }
    }
  }
  __syncthreads();

  // snap near-tied (<= SNAP_ULPS) cross-class scores, earliest class wins.
  // Serial over c2 (fg index); inner scan split over the 4 lanes; min match == first match.
  if (act) {
    for (int c2 = 1; c2 < N_FG; ++c2) {
      float v2 = F[c2 * SMX_ROWS + r];           // broadcast within group
      if (v2 <= 0.0f) continue;
      int u2 = (int)__float_as_uint(v2);
      int found = N_FG;
      for (int c1 = j; c1 < c2; c1 += 4) {
        float v1 = F[c1 * SMX_ROWS + r];
        if (v1 <= 0.0f) continue;
        int du = (int)__float_as_uint(v1) - u2;
        if (du <= SNAP_ULPS && du >= -SNAP_ULPS) { found = c1; break; }
      }
      found = min(found, __shfl_xor(found, 1, 64));
      found = min(found, __shfl_xor(found, 2, 64));
      if (found < c2 && j == 0)
        F[c2 * SMX_ROWS + r] = F[found * SMX_ROWS + r];
    }
  }
  __syncthreads();

  // write transposed fg scores (post-snap values from LDS)
  if (act) {
    float* outb = fgT + (size_t)lb * N_FG * N_PRI + n;
#pragma unroll
    for (int k = 0; k < 21; ++k) {
      int c = j + 4 * k;
      if (c >= 1 && c < N_CLS)
        outb[(size_t)(c - 1) * N_PRI] = F[(c - 1) * SMX_ROWS + r];
    }
  }
}

// ---------------- Stage C: exact top-200 per (b, class), packed u64 keys ----------------
__global__ __launch_bounds__(256) void topk_kernel(const float* __restrict__ fgT,
                                                   float* __restrict__ topk_sc,
                                                   int* __restrict__ topk_idx, int b0) {
  __shared__ unsigned int hist[NBINS];
  __shared__ unsigned long long cand[CANDS];
  __shared__ unsigned int part[256];
  __shared__ int s_cut;
  __shared__ unsigned int s_cnt;
  int t = threadIdx.x;
  int c = blockIdx.x;
  int lb = blockIdx.y;
  int gb = b0 + lb;
  const float* src = fgT + ((size_t)lb * N_FG + c) * N_PRI;

  for (int i = t; i < NBINS; i += 256) hist[i] = 0;
  if (t == 0) s_cnt = 0;
  __syncthreads();

  for (int i = t; i < N_PRI; i += 256) {
    float v = src[i];
    if (v > 0.0f) atomicAdd(&hist[__float_as_uint(v) >> 21], 1u);
  }
  __syncthreads();

  unsigned s = 0;
  for (int j = 0; j < 4; ++j) s += hist[t * 4 + j];
  part[t] = s;
  __syncthreads();

  if (t == 0) {
    unsigned acc = 0; int cut = -1;
    for (int tb = 255; tb >= 0 && cut < 0; --tb) {
      unsigned pa = part[tb];
      if (acc + pa >= PRE) {
        for (int bin = tb * 4 + 3; bin >= tb * 4; --bin) {
          acc += hist[bin];
          if (acc >= PRE) { cut = bin; break; }
        }
      } else acc += pa;
    }
    s_cut = (cut < 0) ? 0 : cut;
  }
  __syncthreads();
  int cut = s_cut;

  for (int i = t; i < N_PRI; i += 256) {
    float v = src[i];
    if (v > 0.0f) {
      unsigned u = __float_as_uint(v);
      if ((int)(u >> 21) >= cut) {
        unsigned pos = atomicAdd(&s_cnt, 1u);
        if (pos < CANDS)
          cand[pos] = ((unsigned long long)u << 32) |
                      (unsigned long long)(0xFFFFFFFFu - (unsigned)i);
      }
    }
  }
  __syncthreads();
  unsigned cnt = s_cnt; if (cnt > CANDS) cnt = CANDS;
  for (int i = t; i < CANDS; i += 256)
    if ((unsigned)i >= cnt) cand[i] = 0ull;
  __syncthreads();

  // bitonic sort descending: value desc, then smaller index first
  for (int k = 2; k <= CANDS; k <<= 1) {
    for (int j = k >> 1; j > 0; j >>= 1) {
      for (int i = t; i < CANDS; i += 256) {
        int ixj = i ^ j;
        if (ixj > i) {
          unsigned long long a = cand[i], bb = cand[ixj];
          bool up = ((i & k) == 0);
          if (up ? (a < bb) : (a > bb)) { cand[i] = bb; cand[ixj] = a; }
        }
      }
      __syncthreads();
    }
  }

  if (t < PRE) {
    unsigned long long key = cand[t];
    float v = __uint_as_float((unsigned)(key >> 32));
    unsigned idx = 0xFFFFFFFFu - (unsigned)(key & 0xFFFFFFFFull);
    if (idx >= N_PRI) idx = 0;
    size_t o = ((size_t)gb * N_FG + c) * PRE + t;
    topk_sc[o] = v;
    topk_idx[o] = (int)idx;
  }
}

// ---------------- Stage D: greedy NMS per (b, class), one wave, f64 IoU ----------------
__global__ __launch_bounds__(64) void nms_kernel(const float* __restrict__ topk_sc,
                                                 const int* __restrict__ topk_idx,
                                                 const double* __restrict__ boxes,
                                                 float* __restrict__ cls_sc) {
  __shared__ double bx[PRE][4];
  __shared__ double ar[PRE];
  __shared__ float sc[PRE];
  __shared__ unsigned char supp[PRE];
  int t = threadIdx.x;
  int c = blockIdx.x, b = blockIdx.y;
  size_t base = ((size_t)b * N_FG + c) * PRE;

  for (int k = t; k < PRE; k += 64) {
    int idx = topk_idx[base + k];
    const double* bp = boxes + ((size_t)b * N_PRI + idx) * 4;
    double x1 = bp[0], y1 = bp[1], x2 = bp[2], y2 = bp[3];
    bx[k][0] = x1; bx[k][1] = y1; bx[k][2] = x2; bx[k][3] = y2;
    ar[k] = fmax(x2 - x1, 0.0) * fmax(y2 - y1, 0.0);
    sc[k] = topk_sc[base + k];
    supp[k] = 0;
  }
  __syncthreads();

  double mybx[4][4]; double mya[4]; bool mykeep[4];
  for (int r = 0; r < 4; ++r) {
    int k = t + r * 64;
    mykeep[r] = false;
    if (k < PRE) {
      mybx[r][0] = bx[k][0]; mybx[r][1] = bx[k][1];
      mybx[r][2] = bx[k][2]; mybx[r][3] = bx[k][3];
      mya[r] = ar[k];
    }
  }

  for (int i = 0; i < PRE; ++i) {
    bool keep_i = (sc[i] > 0.0f) && (supp[i] == 0);
    if ((i & 63) == t) mykeep[i >> 6] = keep_i;
    if (keep_i) {
      double x1 = bx[i][0], y1 = bx[i][1], x2 = bx[i][2], y2 = bx[i][3];
      double ai = ar[i];
      for (int r = 0; r < 4; ++r) {
        int k = t + r * 64;
        if (k < PRE && k > i) {
          double xx1 = fmax(x1, mybx[r][0]), yy1 = fmax(y1, mybx[r][1]);
          double xx2 = fmin(x2, mybx[r][2]), yy2 = fmin(y2, mybx[r][3]);
          double inter = fmax(xx2 - xx1, 0.0) * fmax(yy2 - yy1, 0.0);
          double uni = fmax(ai + mya[r] - inter, 1e-9);
          if (inter / uni > NMS_THR_D) supp[k] = 1;
        }
      }
    }
    __syncthreads();
  }

  for (int r = 0; r < 4; ++r) {
    int k = t + r * 64;
    if (k < PRE) cls_sc[base + k] = mykeep[r] ? sc[k] : 0.0f;
  }
}

// ---------------- Stage E: per-image top-100 + gather outputs ----------------
__global__ __launch_bounds__(256) void final_kernel(const float* __restrict__ cls_sc,
                                                    const int* __restrict__ topk_idx,
                                                    const double* __restrict__ boxes,
                                                    float* __restrict__ out) {
  __shared__ unsigned int hist[NBINS];
  __shared__ unsigned long long cand[CANDS];
  __shared__ unsigned int part[256];
  __shared__ int s_cut;
  __shared__ unsigned int s_cnt;
  const int M = N_FG * PRE;  // 16000
  int t = threadIdx.x, b = blockIdx.x;
  const float* src = cls_sc + (size_t)b * M;

  for (int i = t; i < NBINS; i += 256) hist[i] = 0;
  if (t == 0) s_cnt = 0;
  __syncthreads();

  for (int i = t; i < M; i += 256) {
    float v = src[i];
    if (v > 0.0f) atomicAdd(&hist[__float_as_uint(v) >> 21], 1u);
  }
  __syncthreads();

  unsigned s = 0;
  for (int j = 0; j < 4; ++j) s += hist[t * 4 + j];
  part[t] = s;
  __syncthreads();

  if (t == 0) {
    unsigned acc = 0; int cut = -1;
    for (int tb = 255; tb >= 0 && cut < 0; --tb) {
      unsigned pa = part[tb];
      if (acc + pa >= MAXD) {
        for (int bin = tb * 4 + 3; bin >= tb * 4; --bin) {
          acc += hist[bin];
          if (acc >= MAXD) { cut = bin; break; }
        }
      } else acc += pa;
    }
    s_cut = (cut < 0) ? 0 : cut;
  }
  __syncthreads();
  int cut = s_cut;

  for (int i = t; i < M; i += 256) {
    float v = src[i];
    if (v > 0.0f) {
      unsigned u = __float_as_uint(v);
      if ((int)(u >> 21) >= cut) {
        unsigned pos = atomicAdd(&s_cnt, 1u);
        if (pos < CANDS)
          cand[pos] = ((unsigned long long)u << 32) |
                      (unsigned long long)(0xFFFFFFFFu - (unsigned)i);
      }
    }
  }
  __syncthreads();
  unsigned cnt = s_cnt; if (cnt > CANDS) cnt = CANDS;
  for (int i = t; i < CANDS; i += 256)
    if ((unsigned)i >= cnt) cand[i] = 0ull;
  __syncthreads();

  for (int k = 2; k <= CANDS; k <<= 1) {
    for (int j = k >> 1; j > 0; j >>= 1) {
      for (int i = t; i < CANDS; i += 256) {
        int ixj = i ^ j;
        if (ixj > i) {
          unsigned long long a = cand[i], bb = cand[ixj];
          bool up = ((i & k) == 0);
          if (up ? (a < bb) : (a > bb)) { cand[i] = bb; cand[ixj] = a; }
        }
      }
      __syncthreads();
    }
  }

  if (t < MAXD) {
    unsigned long long key = cand[t];
    float v = __uint_as_float((unsigned)(key >> 32));
    unsigned f = 0xFFFFFFFFu - (unsigned)(key & 0xFFFFFFFFull);
    if (f >= (unsigned)M) f = 0;
    int c = (int)(f / PRE), k = (int)(f % PRE);
    int idx = topk_idx[((size_t)b * N_FG + c) * PRE + k];
    if (idx < 0 || idx >= N_PRI) idx = 0;
    const double* bp = boxes + ((size_t)b * N_PRI + idx) * 4;
    float4 bb = make_float4((float)bp[0], (float)bp[1], (float)bp[2], (float)bp[3]);
    ((float4*)out)[b * MAXD + t] = bb;                              // det_bx
    out[B_IMG * MAXD * 4 + b * MAXD + t] = v;                       // det_sc
    out[B_IMG * MAXD * 5 + b * MAXD + t] = (float)(c + 1);          // det_lb (as float)
  }
}

extern "C" void kernel_launch(void* const* d_in, const int* in_sizes, int n_in,
                              void* d_out, int out_size, void* d_ws, size_t ws_size,
                              hipStream_t stream) {
  const float* cls_logits = (const float*)d_in[0];
  const float* bbox_pred  = (const float*)d_in[1];
  const float* priors     = (const float*)d_in[2];
  float* out = (float*)d_out;

  double* boxes   = (double*)d_ws;                                    // B*N*4 f64
  float* topk_sc  = (float*)(boxes + (size_t)B_IMG * N_PRI * 4);      // B*80*200 f32
  int*   topk_idx = (int*)(topk_sc + (size_t)B_IMG * N_FG * PRE);     // B*80*200 i32
  float* cls_sc   = (float*)(topk_idx + (size_t)B_IMG * N_FG * PRE);  // B*80*200 f32
  float* fgT      = cls_sc + (size_t)B_IMG * N_FG * PRE;              // chunkB*80*N f32

  size_t persist_bytes = (size_t)((char*)fgT - (char*)d_ws);
  size_t per_b = (size_t)N_FG * N_PRI * sizeof(float);
  int chunkB = 1;
  if (ws_size > persist_bytes) {
    size_t cb = (ws_size - persist_bytes) / per_b;
    chunkB = (cb >= (size_t)B_IMG) ? B_IMG : (cb < 1 ? 1 : (int)cb);
  }

  decode_kernel<<<dim3((N_PRI + 255) / 256, B_IMG), 256, 0, stream>>>(
      bbox_pred, priors, boxes);

  for (int b0 = 0; b0 < B_IMG; b0 += chunkB) {
    int nb = (B_IMG - b0) < chunkB ? (B_IMG - b0) : chunkB;
    softmax_fg_kernel<<<dim3((N_PRI + SMX_ROWS - 1) / SMX_ROWS, nb), 64, 0, stream>>>(
        cls_logits, fgT, b0);
    topk_kernel<<<dim3(N_FG, nb), 256, 0, stream>>>(
        fgT, topk_sc, topk_idx, b0);
  }

  nms_kernel<<<dim3(N_FG, B_IMG), 64, 0, stream>>>(
      topk_sc, topk_idx, boxes, cls_sc);

  final_kernel<<<B_IMG, 256, 0, stream>>>(
      cls_sc, topk_idx, boxes, out);
}

// Round 5
// 1220.594 us; speedup vs baseline: 3.6358x; 1.5100x over previous
//
#include <hip/hip_runtime.h>
#include <cstdint>

#define B_IMG 32
#define N_PRI 24564
#define N_CLS 81
#define N_FG  80
#define PRE   200
#define MAXD  100
#define NBINS 1024
#define CANDS 512
#define SNAP_ULPS 2
#define SMX_ROWS 16   // rows per 1-wave block, 4 lanes per row

#define SCORE_THR_F 0.01f
#define NMS_THR_D   0.45
#define CENTER_VAR_D 0.1
#define SIZE_VAR_D   0.2

// ---------------- Stage A: decode boxes (f64) ----------------
__global__ void decode_kernel(const float* __restrict__ bbox,
                              const float* __restrict__ priors,
                              double* __restrict__ boxes) {
  int n = blockIdx.x * blockDim.x + threadIdx.x;
  int b = blockIdx.y;
  if (n >= N_PRI) return;
  float4 loc = ((const float4*)bbox)[(size_t)b * N_PRI + n];
  float4 pr  = ((const float4*)priors)[n];
  double cx = ((double)loc.x * CENTER_VAR_D) * (double)pr.z + (double)pr.x;
  double cy = ((double)loc.y * CENTER_VAR_D) * (double)pr.w + (double)pr.y;
  double w  = exp((double)loc.z * SIZE_VAR_D) * (double)pr.z;
  double h  = exp((double)loc.w * SIZE_VAR_D) * (double)pr.w;
  double* o = boxes + ((size_t)b * N_PRI + n) * 4;
  double2 lo, hi;
  lo.x = cx - w * 0.5; lo.y = cy - h * 0.5;
  hi.x = cx + w * 0.5; hi.y = cy + h * 0.5;
  ((double2*)o)[0] = lo;
  ((double2*)o)[1] = hi;
}

// Fast inline f64 exp for y <= 0 (no specials; ~7e-12 rel err — 4+ orders
// inside the validated 1e-7 selection-robustness margin of this pipeline).
__device__ __forceinline__ double fexp(double y) {
  const double LOG2E = 1.4426950408889634074;
  const double LN2HI = 6.93147180369123816490e-01;
  const double LN2LO = 1.90821492927058770002e-10;
  double kd = rint(y * LOG2E);
  int k = (int)kd;
  if (k < -1020) return 0.0;           // e^y below ~1e-307: contributes nothing
  double r = fma(-kd, LN2HI, y);
  r = fma(-kd, LN2LO, r);
  double p =             2.7557319223985891e-06;   // 1/9!
  p = fma(p, r, 2.4801587301587302e-05);           // 1/8!
  p = fma(p, r, 1.9841269841269841e-04);           // 1/7!
  p = fma(p, r, 1.3888888888888889e-03);           // 1/6!
  p = fma(p, r, 8.3333333333333332e-03);           // 1/5!
  p = fma(p, r, 4.1666666666666664e-02);           // 1/4!
  p = fma(p, r, 1.6666666666666666e-01);           // 1/3!
  p = fma(p, r, 0.5);                              // 1/2!
  p = fma(p, r, 1.0);
  p = fma(p, r, 1.0);
  double s = __longlong_as_double(((long long)(k + 1023)) << 52);
  return p * s;
}

// ---------------- Stage B: f64 softmax -> f32 scores, same-prior ulp-snap, transposed ----------------
// v5: snap restructured — per-lane register mirror pu[21] of the row's thresholded
//     scores (static indexing only), inner scan = 21 register compares (no LDS),
//     outer loop iterates only the row's survivor-mask bits (~31 vs 79) with
//     1-ahead F prefetch. class<c2 filter dropped (min-reduce + found<c2 guard is
//     equivalent; pu==0 auto-fails the unsigned window test). Snap event (rare)
//     updates F + the owner lane's pu slot via unrolled predicated store.
//     No barriers: each 4-lane group touches only its own row's F slots.
__global__ __launch_bounds__(64, 4) void softmax_fg_kernel(
    const float* __restrict__ logits, float* __restrict__ fgT, int b0) {
  __shared__ float F[N_FG * SMX_ROWS];   // F[fg*16 + r], 5120 B
  int t = threadIdx.x;                 // 0..63
  int j = t & 3;                       // lane within 4-lane row group
  int r = t >> 2;                      // row within block, 0..15
  int lb = blockIdx.y;
  int b  = b0 + lb;
  int n  = blockIdx.x * SMX_ROWS + r;
  bool act = (n < N_PRI);

  // load this lane's strided classes (c = j, j+4, ...) and local max
  float lv[21];
  float m = -__builtin_huge_valf();
  if (act) {
    const float* row = logits + ((size_t)b * N_PRI + n) * N_CLS;
#pragma unroll
    for (int k = 0; k < 21; ++k) {
      int c = j + 4 * k;
      if (c < N_CLS) { lv[k] = row[c]; m = fmaxf(m, lv[k]); }
    }
  }
  // group max (fmax assoc/comm, no NaNs) -> same m as serial scan
  m = fmaxf(m, __shfl_xor(m, 1, 64));
  m = fmaxf(m, __shfl_xor(m, 2, 64));
  double dm = (double)m;

  // independent exps -> registers; two partial sums to shorten the dep chain
  // (within-lane order change perturbs d by ~1e-16 rel; cross-lane sum already
  //  relies on commutativity — same safety class, 9 orders inside margin)
  double ev[21];
  double s0 = 0.0, s1 = 0.0;
  if (act) {
#pragma unroll
    for (int k = 0; k < 21; ++k) {
      int c = j + 4 * k;
      if (c < N_CLS) {
        ev[k] = fexp((double)lv[k] - dm);
        if (k & 1) s1 += ev[k]; else s0 += ev[k];
      }
    }
  }
  double s = s0 + s1;
  // 4-lane tree sum -> identical d on all 4 lanes
  s += __shfl_xor(s, 1, 64);
  s += __shfl_xor(s, 2, 64);
  double inv = 1.0 / s;

  // ps: p = (float)(e * (1/d)); threshold; write F + register mirror pu + survivor mask
  unsigned pu[21];
  unsigned long long mlo = 0ull, mhi = 0ull;
  int jm1 = j - 1;
  if (act) {
#pragma unroll
    for (int k = 0; k < 21; ++k) {
      int c = j + 4 * k;
      if (c >= 1 && c < N_CLS) {
        float p = (float)(ev[k] * inv);
        float pv = (p > SCORE_THR_F) ? p : 0.0f;
        F[(c - 1) * SMX_ROWS + r] = pv;
        pu[k] = __float_as_uint(pv);
        if (pu[k] != 0u) {
          int f = 4 * k + jm1;                 // fg class index
          if (f < 64) mlo |= 1ull << f;
          else        mhi |= 1ull << (f - 64);
        }
      } else pu[k] = 0u;
    }
  }
  // group-OR survivor masks (group-uniform control flow; partners co-active)
  mlo |= __shfl_xor(mlo, 1, 64);
  mlo |= __shfl_xor(mlo, 2, 64);
  mhi |= __shfl_xor(mhi, 1, 64);
  mhi |= __shfl_xor(mhi, 2, 64);

  // snap near-tied (<= SNAP_ULPS) scores, earliest class wins, serial in c2
  // over survivors only. Semantics identical to the serial c2=1..79 loop:
  // min matching class (self/higher classes filtered by the found<c2 guard),
  // current values via pu mirror (updated on snap).
  if (act) {
    unsigned long long mask  = mlo & ~1ull;    // fg 0 never a snap target
    unsigned long long maskh = mhi;
    // first survivor
    int c2 = -1;
    if (mask)       { c2 = __ffsll(mask) - 1;       mask  &= mask - 1; }
    else if (maskh) { c2 = 64 + __ffsll(maskh) - 1; maskh &= maskh - 1; }
    float v2 = (c2 >= 0) ? F[c2 * SMX_ROWS + r] : 0.0f;
    while (c2 >= 0) {
      // prefetch next survivor's value (snap writes only F[c2], never future)
      int c2n = -1;
      if (mask)       { c2n = __ffsll(mask) - 1;       mask  &= mask - 1; }
      else if (maskh) { c2n = 64 + __ffsll(maskh) - 1; maskh &= maskh - 1; }
      float vnext = (c2n >= 0) ? F[c2n * SMX_ROWS + r] : 0.0f;

      unsigned u2m = __float_as_uint(v2) - 2u;
      int found = 255;
#pragma unroll
      for (int k = 0; k < 21; ++k) {
        unsigned du = pu[k] - u2m;             // pu==0 -> huge -> auto-fail
        int cls = 4 * k + jm1;
        if (du <= 4u) found = min(found, cls);
      }
      found = min(found, __shfl_xor(found, 1, 64));
      found = min(found, __shfl_xor(found, 2, 64));
      if (found < c2) {                        // rare
        float vf = F[found * SMX_ROWS + r];    // broadcast read (same addr)
        if (j == 0) F[c2 * SMX_ROWS + r] = vf;
        int kk = (c2 + 1) >> 2;
        if (((c2 + 1) & 3) == j) {             // owner lane updates mirror
          unsigned nb = __float_as_uint(vf);
#pragma unroll
          for (int k = 0; k < 21; ++k) if (k == kk) pu[k] = nb;
        }
      }
      c2 = c2n; v2 = vnext;
    }
  }

  // write transposed fg scores straight from the register mirror
  if (act) {
    float* outb = fgT + (size_t)lb * N_FG * N_PRI + n;
#pragma unroll
    for (int k = 0; k < 21; ++k) {
      int c = j + 4 * k;
      if (c >= 1 && c < N_CLS)
        outb[(size_t)(c - 1) * N_PRI] = __uint_as_float(pu[k]);
    }
  }
}

// ---------------- Stage C: exact top-200 per (b, class), packed u64 keys ----------------
__global__ __launch_bounds__(256) void topk_kernel(const float* __restrict__ fgT,
                                                   float* __restrict__ topk_sc,
                                                   int* __restrict__ topk_idx, int b0) {
  __shared__ unsigned int hist[NBINS];
  __shared__ unsigned long long cand[CANDS];
  __shared__ unsigned int part[256];
  __shared__ int s_cut;
  __shared__ unsigned int s_cnt;
  int t = threadIdx.x;
  int c = blockIdx.x;
  int lb = blockIdx.y;
  int gb = b0 + lb;
  const float* src = fgT + ((size_t)lb * N_FG + c) * N_PRI;

  for (int i = t; i < NBINS; i += 256) hist[i] = 0;
  if (t == 0) s_cnt = 0;
  __syncthreads();

  for (int i = t; i < N_PRI; i += 256) {
    float v = src[i];
    if (v > 0.0f) atomicAdd(&hist[__float_as_uint(v) >> 21], 1u);
  }
  __syncthreads();

  unsigned s = 0;
  for (int j = 0; j < 4; ++j) s += hist[t * 4 + j];
  part[t] = s;
  __syncthreads();

  if (t == 0) {
    unsigned acc = 0; int cut = -1;
    for (int tb = 255; tb >= 0 && cut < 0; --tb) {
      unsigned pa = part[tb];
      if (acc + pa >= PRE) {
        for (int bin = tb * 4 + 3; bin >= tb * 4; --bin) {
          acc += hist[bin];
          if (acc >= PRE) { cut = bin; break; }
        }
      } else acc += pa;
    }
    s_cut = (cut < 0) ? 0 : cut;
  }
  __syncthreads();
  int cut = s_cut;

  for (int i = t; i < N_PRI; i += 256) {
    float v = src[i];
    if (v > 0.0f) {
      unsigned u = __float_as_uint(v);
      if ((int)(u >> 21) >= cut) {
        unsigned pos = atomicAdd(&s_cnt, 1u);
        if (pos < CANDS)
          cand[pos] = ((unsigned long long)u << 32) |
                      (unsigned long long)(0xFFFFFFFFu - (unsigned)i);
      }
    }
  }
  __syncthreads();
  unsigned cnt = s_cnt; if (cnt > CANDS) cnt = CANDS;
  for (int i = t; i < CANDS; i += 256)
    if ((unsigned)i >= cnt) cand[i] = 0ull;
  __syncthreads();

  // bitonic sort descending: value desc, then smaller index first
  for (int k = 2; k <= CANDS; k <<= 1) {
    for (int j = k >> 1; j > 0; j >>= 1) {
      for (int i = t; i < CANDS; i += 256) {
        int ixj = i ^ j;
        if (ixj > i) {
          unsigned long long a = cand[i], bb = cand[ixj];
          bool up = ((i & k) == 0);
          if (up ? (a < bb) : (a > bb)) { cand[i] = bb; cand[ixj] = a; }
        }
      }
      __syncthreads();
    }
  }

  if (t < PRE) {
    unsigned long long key = cand[t];
    float v = __uint_as_float((unsigned)(key >> 32));
    unsigned idx = 0xFFFFFFFFu - (unsigned)(key & 0xFFFFFFFFull);
    if (idx >= N_PRI) idx = 0;
    size_t o = ((size_t)gb * N_FG + c) * PRE + t;
    topk_sc[o] = v;
    topk_idx[o] = (int)idx;
  }
}

// ---------------- Stage D: greedy NMS per (b, class), one wave, f64 IoU ----------------
__global__ __launch_bounds__(64) void nms_kernel(const float* __restrict__ topk_sc,
                                                 const int* __restrict__ topk_idx,
                                                 const double* __restrict__ boxes,
                                                 float* __restrict__ cls_sc) {
  __shared__ double bx[PRE][4];
  __shared__ double ar[PRE];
  __shared__ float sc[PRE];
  __shared__ unsigned char supp[PRE];
  int t = threadIdx.x;
  int c = blockIdx.x, b = blockIdx.y;
  size_t base = ((size_t)b * N_FG + c) * PRE;

  for (int k = t; k < PRE; k += 64) {
    int idx = topk_idx[base + k];
    const double* bp = boxes + ((size_t)b * N_PRI + idx) * 4;
    double x1 = bp[0], y1 = bp[1], x2 = bp[2], y2 = bp[3];
    bx[k][0] = x1; bx[k][1] = y1; bx[k][2] = x2; bx[k][3] = y2;
    ar[k] = fmax(x2 - x1, 0.0) * fmax(y2 - y1, 0.0);
    sc[k] = topk_sc[base + k];
    supp[k] = 0;
  }
  __syncthreads();

  double mybx[4][4]; double mya[4]; bool mykeep[4];
  for (int r = 0; r < 4; ++r) {
    int k = t + r * 64;
    mykeep[r] = false;
    if (k < PRE) {
      mybx[r][0] = bx[k][0]; mybx[r][1] = bx[k][1];
      mybx[r][2] = bx[k][2]; mybx[r][3] = bx[k][3];
      mya[r] = ar[k];
    }
  }

  for (int i = 0; i < PRE; ++i) {
    bool keep_i = (sc[i] > 0.0f) && (supp[i] == 0);
    if ((i & 63) == t) mykeep[i >> 6] = keep_i;
    if (keep_i) {
      double x1 = bx[i][0], y1 = bx[i][1], x2 = bx[i][2], y2 = bx[i][3];
      double ai = ar[i];
      for (int r = 0; r < 4; ++r) {
        int k = t + r * 64;
        if (k < PRE && k > i) {
          double xx1 = fmax(x1, mybx[r][0]), yy1 = fmax(y1, mybx[r][1]);
          double xx2 = fmin(x2, mybx[r][2]), yy2 = fmin(y2, mybx[r][3]);
          double inter = fmax(xx2 - xx1, 0.0) * fmax(yy2 - yy1, 0.0);
          double uni = fmax(ai + mya[r] - inter, 1e-9);
          if (inter / uni > NMS_THR_D) supp[k] = 1;
        }
      }
    }
    __syncthreads();
  }

  for (int r = 0; r < 4; ++r) {
    int k = t + r * 64;
    if (k < PRE) cls_sc[base + k] = mykeep[r] ? sc[k] : 0.0f;
  }
}

// ---------------- Stage E: per-image top-100 + gather outputs ----------------
__global__ __launch_bounds__(256) void final_kernel(const float* __restrict__ cls_sc,
                                                    const int* __restrict__ topk_idx,
                                                    const double* __restrict__ boxes,
                                                    float* __restrict__ out) {
  __shared__ unsigned int hist[NBINS];
  __shared__ unsigned long long cand[CANDS];
  __shared__ unsigned int part[256];
  __shared__ int s_cut;
  __shared__ unsigned int s_cnt;
  const int M = N_FG * PRE;  // 16000
  int t = threadIdx.x, b = blockIdx.x;
  const float* src = cls_sc + (size_t)b * M;

  for (int i = t; i < NBINS; i += 256) hist[i] = 0;
  if (t == 0) s_cnt = 0;
  __syncthreads();

  for (int i = t; i < M; i += 256) {
    float v = src[i];
    if (v > 0.0f) atomicAdd(&hist[__float_as_uint(v) >> 21], 1u);
  }
  __syncthreads();

  unsigned s = 0;
  for (int j = 0; j < 4; ++j) s += hist[t * 4 + j];
  part[t] = s;
  __syncthreads();

  if (t == 0) {
    unsigned acc = 0; int cut = -1;
    for (int tb = 255; tb >= 0 && cut < 0; --tb) {
      unsigned pa = part[tb];
      if (acc + pa >= MAXD) {
        for (int bin = tb * 4 + 3; bin >= tb * 4; --bin) {
          acc += hist[bin];
          if (acc >= MAXD) { cut = bin; break; }
        }
      } else acc += pa;
    }
    s_cut = (cut < 0) ? 0 : cut;
  }
  __syncthreads();
  int cut = s_cut;

  for (int i = t; i < M; i += 256) {
    float v = src[i];
    if (v > 0.0f) {
      unsigned u = __float_as_uint(v);
      if ((int)(u >> 21) >= cut) {
        unsigned pos = atomicAdd(&s_cnt, 1u);
        if (pos < CANDS)
          cand[pos] = ((unsigned long long)u << 32) |
                      (unsigned long long)(0xFFFFFFFFu - (unsigned)i);
      }
    }
  }
  __syncthreads();
  unsigned cnt = s_cnt; if (cnt > CANDS) cnt = CANDS;
  for (int i = t; i < CANDS; i += 256)
    if ((unsigned)i >= cnt) cand[i] = 0ull;
  __syncthreads();

  for (int k = 2; k <= CANDS; k <<= 1) {
    for (int j = k >> 1; j > 0; j >>= 1) {
      for (int i = t; i < CANDS; i += 256) {
        int ixj = i ^ j;
        if (ixj > i) {
          unsigned long long a = cand[i], bb = cand[ixj];
          bool up = ((i & k) == 0);
          if (up ? (a < bb) : (a > bb)) { cand[i] = bb; cand[ixj] = a; }
        }
      }
      __syncthreads();
    }
  }

  if (t < MAXD) {
    unsigned long long key = cand[t];
    float v = __uint_as_float((unsigned)(key >> 32));
    unsigned f = 0xFFFFFFFFu - (unsigned)(key & 0xFFFFFFFFull);
    if (f >= (unsigned)M) f = 0;
    int c = (int)(f / PRE), k = (int)(f % PRE);
    int idx = topk_idx[((size_t)b * N_FG + c) * PRE + k];
    if (idx < 0 || idx >= N_PRI) idx = 0;
    const double* bp = boxes + ((size_t)b * N_PRI + idx) * 4;
    float4 bb = make_float4((float)bp[0], (float)bp[1], (float)bp[2], (float)bp[3]);
    ((float4*)out)[b * MAXD + t] = bb;                              // det_bx
    out[B_IMG * MAXD * 4 + b * MAXD + t] = v;                       // det_sc
    out[B_IMG * MAXD * 5 + b * MAXD + t] = (float)(c + 1);          // det_lb (as float)
  }
}

extern "C" void kernel_launch(void* const* d_in, const int* in_sizes, int n_in,
                              void* d_out, int out_size, void* d_ws, size_t ws_size,
                              hipStream_t stream) {
  const float* cls_logits = (const float*)d_in[0];
  const float* bbox_pred  = (const float*)d_in[1];
  const float* priors     = (const float*)d_in[2];
  float* out = (float*)d_out;

  double* boxes   = (double*)d_ws;                                    // B*N*4 f64
  float* topk_sc  = (float*)(boxes + (size_t)B_IMG * N_PRI * 4);      // B*80*200 f32
  int*   topk_idx = (int*)(topk_sc + (size_t)B_IMG * N_FG * PRE);     // B*80*200 i32
  float* cls_sc   = (float*)(topk_idx + (size_t)B_IMG * N_FG * PRE);  // B*80*200 f32
  float* fgT      = cls_sc + (size_t)B_IMG * N_FG * PRE;              // chunkB*80*N f32

  size_t persist_bytes = (size_t)((char*)fgT - (char*)d_ws);
  size_t per_b = (size_t)N_FG * N_PRI * sizeof(float);
  int chunkB = 1;
  if (ws_size > persist_bytes) {
    size_t cb = (ws_size - persist_bytes) / per_b;
    chunkB = (cb >= (size_t)B_IMG) ? B_IMG : (cb < 1 ? 1 : (int)cb);
  }

  decode_kernel<<<dim3((N_PRI + 255) / 256, B_IMG), 256, 0, stream>>>(
      bbox_pred, priors, boxes);

  for (int b0 = 0; b0 < B_IMG; b0 += chunkB) {
    int nb = (B_IMG - b0) < chunkB ? (B_IMG - b0) : chunkB;
    softmax_fg_kernel<<<dim3((N_PRI + SMX_ROWS - 1) / SMX_ROWS, nb), 64, 0, stream>>>(
        cls_logits, fgT, b0);
    topk_kernel<<<dim3(N_FG, nb), 256, 0, stream>>>(
        fgT, topk_sc, topk_idx, b0);
  }

  nms_kernel<<<dim3(N_FG, B_IMG), 64, 0, stream>>>(
      topk_sc, topk_idx, boxes, cls_sc);

  final_kernel<<<B_IMG, 256, 0, stream>>>(
      cls_sc, topk_idx, boxes, out);
}

// Round 7
// 1098.319 us; speedup vs baseline: 4.0406x; 1.1113x over previous
//
#include <hip/hip_runtime.h>
#include <cstdint>

#define B_IMG 32
#define N_PRI 24564
#define N_CLS 81
#define N_FG  80
#define PRE   200
#define MAXD  100
#define NBINS 1024
#define CANDS 512
#define SNAP_ULPS 2
#define SMX_ROWS 16   // rows per 1-wave block, 4 lanes per row

#define SCORE_THR_F 0.01f
#define NMS_THR_D   0.45
#define CENTER_VAR_D 0.1
#define SIZE_VAR_D   0.2

// Fast inline f64 exp (no specials; args here are in [-12, 2] so no range
// guard needed; single-word LN2 reduction adds ~4e-15 rel err — 8 orders
// inside the validated 1e-7 selection-robustness margin).
__device__ __forceinline__ double fexp(double y) {
  const double LOG2E = 1.4426950408889634074;
  const double LN2   = 0.69314718055994530942;
  double kd = rint(y * LOG2E);
  double r = fma(-kd, LN2, y);
  double p =             2.7557319223985891e-06;   // 1/9!
  p = fma(p, r, 2.4801587301587302e-05);           // 1/8!
  p = fma(p, r, 1.9841269841269841e-04);           // 1/7!
  p = fma(p, r, 1.3888888888888889e-03);           // 1/6!
  p = fma(p, r, 8.3333333333333332e-03);           // 1/5!
  p = fma(p, r, 4.1666666666666664e-02);           // 1/4!
  p = fma(p, r, 1.6666666666666666e-01);           // 1/3!
  p = fma(p, r, 0.5);                              // 1/2!
  p = fma(p, r, 1.0);
  p = fma(p, r, 1.0);
  int k = (int)kd;
  double s = __longlong_as_double(((long long)(k + 1023)) << 52);
  return p * s;
}

// quad (4-lane) min via DPP quad_perm — replaces 2 ds_swizzle shfls with 2 VALU ops
__device__ __forceinline__ int qmin4(int x) {
  int y = __builtin_amdgcn_mov_dpp(x, 0xB1, 0xf, 0xf, true);  // quad_perm [1,0,3,2]
  x = min(x, y);
  y = __builtin_amdgcn_mov_dpp(x, 0x4E, 0xf, 0xf, true);      // quad_perm [2,3,0,1]
  return min(x, y);
}

// ---------------- Stage A: decode boxes (f64) ----------------
__global__ void decode_kernel(const float* __restrict__ bbox,
                              const float* __restrict__ priors,
                              double* __restrict__ boxes) {
  int n = blockIdx.x * blockDim.x + threadIdx.x;
  int b = blockIdx.y;
  if (n >= N_PRI) return;
  float4 loc = ((const float4*)bbox)[(size_t)b * N_PRI + n];
  float4 pr  = ((const float4*)priors)[n];
  double cx = ((double)loc.x * CENTER_VAR_D) * (double)pr.z + (double)pr.x;
  double cy = ((double)loc.y * CENTER_VAR_D) * (double)pr.w + (double)pr.y;
  double w  = fexp((double)loc.z * SIZE_VAR_D) * (double)pr.z;
  double h  = fexp((double)loc.w * SIZE_VAR_D) * (double)pr.w;
  double* o = boxes + ((size_t)b * N_PRI + n) * 4;
  double2 lo, hi;
  lo.x = cx - w * 0.5; lo.y = cy - h * 0.5;
  hi.x = cx + w * 0.5; hi.y = cy + h * 0.5;
  ((double2*)o)[0] = lo;
  ((double2*)o)[1] = hi;
}

// ---------------- Stage B: f64 softmax -> f32 scores, same-prior ulp-snap, transposed ----------------
// v6: __launch_bounds__(64,2) stops the ev[]/pu[] scratch spill (VGPR was 48 with
//     ~105 live regs -> ~56MB HBM scratch leak); snap's per-iteration 4-lane min
//     reduce moved from ds_swizzle shfls to DPP quad_perm (pure VALU); fexp
//     trimmed (no range branch, single-word LN2). Semantics unchanged vs v5.
__global__ __launch_bounds__(64, 2) void softmax_fg_kernel(
    const float* __restrict__ logits, float* __restrict__ fgT, int b0) {
  __shared__ float F[N_FG * SMX_ROWS];   // F[fg*16 + r], 5120 B
  int t = threadIdx.x;                 // 0..63
  int j = t & 3;                       // lane within 4-lane row group
  int r = t >> 2;                      // row within block, 0..15
  int lb = blockIdx.y;
  int b  = b0 + lb;
  int n  = blockIdx.x * SMX_ROWS + r;
  bool act = (n < N_PRI);

  // load this lane's strided classes (c = j, j+4, ...) and local max
  float lv[21];
  float m = -__builtin_huge_valf();
  if (act) {
    const float* row = logits + ((size_t)b * N_PRI + n) * N_CLS;
#pragma unroll
    for (int k = 0; k < 21; ++k) {
      int c = j + 4 * k;
      if (c < N_CLS) { lv[k] = row[c]; m = fmaxf(m, lv[k]); }
    }
  }
  // group max (fmax assoc/comm, no NaNs) -> same m as serial scan
  m = fmaxf(m, __shfl_xor(m, 1, 64));
  m = fmaxf(m, __shfl_xor(m, 2, 64));
  double dm = (double)m;

  // independent exps -> registers; two partial sums to shorten the dep chain
  double ev[21];
  double s0 = 0.0, s1 = 0.0;
  if (act) {
#pragma unroll
    for (int k = 0; k < 21; ++k) {
      int c = j + 4 * k;
      if (c < N_CLS) {
        ev[k] = fexp((double)lv[k] - dm);
        if (k & 1) s1 += ev[k]; else s0 += ev[k];
      }
    }
  }
  double s = s0 + s1;
  // 4-lane tree sum -> identical d on all 4 lanes
  s += __shfl_xor(s, 1, 64);
  s += __shfl_xor(s, 2, 64);
  double inv = 1.0 / s;

  // ps: p = (float)(e * (1/d)); threshold; write F + register mirror pu + survivor mask
  unsigned pu[21];
  unsigned long long mlo = 0ull, mhi = 0ull;
  int jm1 = j - 1;
  if (act) {
#pragma unroll
    for (int k = 0; k < 21; ++k) {
      int c = j + 4 * k;
      if (c >= 1 && c < N_CLS) {
        float p = (float)(ev[k] * inv);
        float pv = (p > SCORE_THR_F) ? p : 0.0f;
        F[(c - 1) * SMX_ROWS + r] = pv;
        pu[k] = __float_as_uint(pv);
        if (pu[k] != 0u) {
          int f = 4 * k + jm1;                 // fg class index
          if (f < 64) mlo |= 1ull << f;
          else        mhi |= 1ull << (f - 64);
        }
      } else pu[k] = 0u;
    }
  }
  // group-OR survivor masks (group-uniform control flow; partners co-active)
  mlo |= __shfl_xor(mlo, 1, 64);
  mlo |= __shfl_xor(mlo, 2, 64);
  mhi |= __shfl_xor(mhi, 1, 64);
  mhi |= __shfl_xor(mhi, 2, 64);

  // snap near-tied (<= SNAP_ULPS) scores, earliest class wins, serial in c2
  // over survivors only. Semantics identical to the serial c2=1..79 loop.
  if (act) {
    unsigned long long mask  = mlo & ~1ull;    // fg 0 never a snap target
    unsigned long long maskh = mhi;
    int c2 = -1;
    if (mask)       { c2 = __ffsll(mask) - 1;       mask  &= mask - 1; }
    else if (maskh) { c2 = 64 + __ffsll(maskh) - 1; maskh &= maskh - 1; }
    float v2 = (c2 >= 0) ? F[c2 * SMX_ROWS + r] : 0.0f;
    while (c2 >= 0) {
      // prefetch next survivor's value (snap writes only F[c2], never future)
      int c2n = -1;
      if (mask)       { c2n = __ffsll(mask) - 1;       mask  &= mask - 1; }
      else if (maskh) { c2n = 64 + __ffsll(maskh) - 1; maskh &= maskh - 1; }
      float vnext = (c2n >= 0) ? F[c2n * SMX_ROWS + r] : 0.0f;

      unsigned u2m = __float_as_uint(v2) - 2u;
      int found = 255;
#pragma unroll
      for (int k = 0; k < 21; ++k) {
        unsigned du = pu[k] - u2m;             // pu==0 -> huge -> auto-fail
        int cls = 4 * k + jm1;
        if (du <= 4u) found = min(found, cls);
      }
      found = qmin4(found);                    // DPP quad min (VALU-only)
      if (found < c2) {                        // rare
        float vf = F[found * SMX_ROWS + r];    // broadcast read (same addr)
        if (j == 0) F[c2 * SMX_ROWS + r] = vf;
        int kk = (c2 + 1) >> 2;
        if (((c2 + 1) & 3) == j) {             // owner lane updates mirror
          unsigned nb = __float_as_uint(vf);
#pragma unroll
          for (int k = 0; k < 21; ++k) if (k == kk) pu[k] = nb;
        }
      }
      c2 = c2n; v2 = vnext;
    }
  }

  // write transposed fg scores straight from the register mirror
  if (act) {
    float* outb = fgT + (size_t)lb * N_FG * N_PRI + n;
#pragma unroll
    for (int k = 0; k < 21; ++k) {
      int c = j + 4 * k;
      if (c >= 1 && c < N_CLS)
        outb[(size_t)(c - 1) * N_PRI] = __uint_as_float(pu[k]);
    }
  }
}

// ---------------- Stage C: exact top-200 per (b, class), packed u64 keys ----------------
// v6: float4 scans (N_PRI/4 exact, 16B-aligned bases); 4 per-wave sub-histograms
//     cut LDS same-bin atomic contention 4x.
__global__ __launch_bounds__(256) void topk_kernel(const float* __restrict__ fgT,
                                                   float* __restrict__ topk_sc,
                                                   int* __restrict__ topk_idx, int b0) {
  __shared__ unsigned int hist[4][NBINS];
  __shared__ unsigned long long cand[CANDS];
  __shared__ unsigned int part[256];
  __shared__ int s_cut;
  __shared__ unsigned int s_cnt;
  int t = threadIdx.x;
  int w = t >> 6;                       // wave id 0..3
  int c = blockIdx.x;
  int lb = blockIdx.y;
  int gb = b0 + lb;
  const float* src = fgT + ((size_t)lb * N_FG + c) * N_PRI;
  const float4* src4 = (const float4*)src;

  unsigned int* hf = &hist[0][0];
  for (int i = t; i < 4 * NBINS; i += 256) hf[i] = 0;
  if (t == 0) s_cnt = 0;
  __syncthreads();

  for (int i = t; i < N_PRI / 4; i += 256) {
    float4 v = src4[i];
    if (v.x > 0.0f) atomicAdd(&hist[w][__float_as_uint(v.x) >> 21], 1u);
    if (v.y > 0.0f) atomicAdd(&hist[w][__float_as_uint(v.y) >> 21], 1u);
    if (v.z > 0.0f) atomicAdd(&hist[w][__float_as_uint(v.z) >> 21], 1u);
    if (v.w > 0.0f) atomicAdd(&hist[w][__float_as_uint(v.w) >> 21], 1u);
  }
  __syncthreads();

  unsigned s = 0;
  for (int jj = 0; jj < 4; ++jj) {
    int bin = t * 4 + jj;
    s += hist[0][bin] + hist[1][bin] + hist[2][bin] + hist[3][bin];
  }
  part[t] = s;
  __syncthreads();

  if (t == 0) {
    unsigned acc = 0; int cut = -1;
    for (int tb = 255; tb >= 0 && cut < 0; --tb) {
      unsigned pa = part[tb];
      if (acc + pa >= PRE) {
        for (int bin = tb * 4 + 3; bin >= tb * 4; --bin) {
          acc += hist[0][bin] + hist[1][bin] + hist[2][bin] + hist[3][bin];
          if (acc >= PRE) { cut = bin; break; }
        }
      } else acc += pa;
    }
    s_cut = (cut < 0) ? 0 : cut;
  }
  __syncthreads();
  int cut = s_cut;

  for (int i = t; i < N_PRI / 4; i += 256) {
    float4 v = src4[i];
    float vv[4] = {v.x, v.y, v.z, v.w};
#pragma unroll
    for (int e = 0; e < 4; ++e) {
      if (vv[e] > 0.0f) {
        unsigned u = __float_as_uint(vv[e]);
        if ((int)(u >> 21) >= cut) {
          unsigned pos = atomicAdd(&s_cnt, 1u);
          if (pos < CANDS)
            cand[pos] = ((unsigned long long)u << 32) |
                        (unsigned long long)(0xFFFFFFFFu - (unsigned)(4 * i + e));
        }
      }
    }
  }
  __syncthreads();
  unsigned cnt = s_cnt; if (cnt > CANDS) cnt = CANDS;
  for (int i = t; i < CANDS; i += 256)
    if ((unsigned)i >= cnt) cand[i] = 0ull;
  __syncthreads();

  // bitonic sort descending: value desc, then smaller index first
  for (int k = 2; k <= CANDS; k <<= 1) {
    for (int jj = k >> 1; jj > 0; jj >>= 1) {
      for (int i = t; i < CANDS; i += 256) {
        int ixj = i ^ jj;
        if (ixj > i) {
          unsigned long long a = cand[i], bb = cand[ixj];
          bool up = ((i & k) == 0);
          if (up ? (a < bb) : (a > bb)) { cand[i] = bb; cand[ixj] = a; }
        }
      }
      __syncthreads();
    }
  }

  if (t < PRE) {
    unsigned long long key = cand[t];
    float v = __uint_as_float((unsigned)(key >> 32));
    unsigned idx = 0xFFFFFFFFu - (unsigned)(key & 0xFFFFFFFFull);
    if (idx >= N_PRI) idx = 0;
    size_t o = ((size_t)gb * N_FG + c) * PRE + t;
    topk_sc[o] = v;
    topk_idx[o] = (int)idx;
  }
}

// ---------------- Stage D: greedy NMS per (b, class), one wave, f64 IoU ----------------
__global__ __launch_bounds__(64) void nms_kernel(const float* __restrict__ topk_sc,
                                                 const int* __restrict__ topk_idx,
                                                 const double* __restrict__ boxes,
                                                 float* __restrict__ cls_sc) {
  __shared__ double bx[PRE][4];
  __shared__ double ar[PRE];
  __shared__ float sc[PRE];
  __shared__ unsigned char supp[PRE];
  int t = threadIdx.x;
  int c = blockIdx.x, b = blockIdx.y;
  size_t base = ((size_t)b * N_FG + c) * PRE;

  for (int k = t; k < PRE; k += 64) {
    int idx = topk_idx[base + k];
    const double* bp = boxes + ((size_t)b * N_PRI + idx) * 4;
    double x1 = bp[0], y1 = bp[1], x2 = bp[2], y2 = bp[3];
    bx[k][0] = x1; bx[k][1] = y1; bx[k][2] = x2; bx[k][3] = y2;
    ar[k] = fmax(x2 - x1, 0.0) * fmax(y2 - y1, 0.0);
    sc[k] = topk_sc[base + k];
    supp[k] = 0;
  }
  __syncthreads();

  double mybx[4][4]; double mya[4]; bool mykeep[4];
  for (int r = 0; r < 4; ++r) {
    int k = t + r * 64;
    mykeep[r] = false;
    if (k < PRE) {
      mybx[r][0] = bx[k][0]; mybx[r][1] = bx[k][1];
      mybx[r][2] = bx[k][2]; mybx[r][3] = bx[k][3];
      mya[r] = ar[k];
    }
  }

  for (int i = 0; i < PRE; ++i) {
    bool keep_i = (sc[i] > 0.0f) && (supp[i] == 0);
    if ((i & 63) == t) mykeep[i >> 6] = keep_i;
    if (keep_i) {
      double x1 = bx[i][0], y1 = bx[i][1], x2 = bx[i][2], y2 = bx[i][3];
      double ai = ar[i];
      for (int r = 0; r < 4; ++r) {
        int k = t + r * 64;
        if (k < PRE && k > i) {
          double xx1 = fmax(x1, mybx[r][0]), yy1 = fmax(y1, mybx[r][1]);
          double xx2 = fmin(x2, mybx[r][2]), yy2 = fmin(y2, mybx[r][3]);
          double inter = fmax(xx2 - xx1, 0.0) * fmax(yy2 - yy1, 0.0);
          double uni = fmax(ai + mya[r] - inter, 1e-9);
          if (inter / uni > NMS_THR_D) supp[k] = 1;
        }
      }
    }
    __syncthreads();
  }

  for (int r = 0; r < 4; ++r) {
    int k = t + r * 64;
    if (k < PRE) cls_sc[base + k] = mykeep[r] ? sc[k] : 0.0f;
  }
}

// ---------------- Stage E: per-image top-100 + gather outputs ----------------
__global__ __launch_bounds__(256) void final_kernel(const float* __restrict__ cls_sc,
                                                    const int* __restrict__ topk_idx,
                                                    const double* __restrict__ boxes,
                                                    float* __restrict__ out) {
  __shared__ unsigned int hist[NBINS];
  __shared__ unsigned long long cand[CANDS];
  __shared__ unsigned int part[256];
  __shared__ int s_cut;
  __shared__ unsigned int s_cnt;
  const int M = N_FG * PRE;  // 16000
  int t = threadIdx.x, b = blockIdx.x;
  const float* src = cls_sc + (size_t)b * M;
  const float4* src4 = (const float4*)src;

  for (int i = t; i < NBINS; i += 256) hist[i] = 0;
  if (t == 0) s_cnt = 0;
  __syncthreads();

  for (int i = t; i < M / 4; i += 256) {
    float4 v = src4[i];
    if (v.x > 0.0f) atomicAdd(&hist[__float_as_uint(v.x) >> 21], 1u);
    if (v.y > 0.0f) atomicAdd(&hist[__float_as_uint(v.y) >> 21], 1u);
    if (v.z > 0.0f) atomicAdd(&hist[__float_as_uint(v.z) >> 21], 1u);
    if (v.w > 0.0f) atomicAdd(&hist[__float_as_uint(v.w) >> 21], 1u);
  }
  __syncthreads();

  unsigned s = 0;
  for (int jj = 0; jj < 4; ++jj) s += hist[t * 4 + jj];
  part[t] = s;
  __syncthreads();

  if (t == 0) {
    unsigned acc = 0; int cut = -1;
    for (int tb = 255; tb >= 0 && cut < 0; --tb) {
      unsigned pa = part[tb];
      if (acc + pa >= MAXD) {
        for (int bin = tb * 4 + 3; bin >= tb * 4; --bin) {
          acc += hist[bin];
          if (acc >= MAXD) { cut = bin; break; }
        }
      } else acc += pa;
    }
    s_cut = (cut < 0) ? 0 : cut;
  }
  __syncthreads();
  int cut = s_cut;

  for (int i = t; i < M / 4; i += 256) {
    float4 v = src4[i];
    float vv[4] = {v.x, v.y, v.z, v.w};
#pragma unroll
    for (int e = 0; e < 4; ++e) {
      if (vv[e] > 0.0f) {
        unsigned u = __float_as_uint(vv[e]);
        if ((int)(u >> 21) >= cut) {
          unsigned pos = atomicAdd(&s_cnt, 1u);
          if (pos < CANDS)
            cand[pos] = ((unsigned long long)u << 32) |
                        (unsigned long long)(0xFFFFFFFFu - (unsigned)(4 * i + e));
        }
      }
    }
  }
  __syncthreads();
  unsigned cnt = s_cnt; if (cnt > CANDS) cnt = CANDS;
  for (int i = t; i < CANDS; i += 256)
    if ((unsigned)i >= cnt) cand[i] = 0ull;
  __syncthreads();

  for (int k = 2; k <= CANDS; k <<= 1) {
    for (int jj = k >> 1; jj > 0; jj >>= 1) {
      for (int i = t; i < CANDS; i += 256) {
        int ixj = i ^ jj;
        if (ixj > i) {
          unsigned long long a = cand[i], bb = cand[ixj];
          bool up = ((i & k) == 0);
          if (up ? (a < bb) : (a > bb)) { cand[i] = bb; cand[ixj] = a; }
        }
      }
      __syncthreads();
    }
  }

  if (t < MAXD) {
    unsigned long long key = cand[t];
    float v = __uint_as_float((unsigned)(key >> 32));
    unsigned f = 0xFFFFFFFFu - (unsigned)(key & 0xFFFFFFFFull);
    if (f >= (unsigned)M) f = 0;
    int c = (int)(f / PRE), k = (int)(f % PRE);
    int idx = topk_idx[((size_t)b * N_FG + c) * PRE + k];
    if (idx < 0 || idx >= N_PRI) idx = 0;
    const double* bp = boxes + ((size_t)b * N_PRI + idx) * 4;
    float4 bb = make_float4((float)bp[0], (float)bp[1], (float)bp[2], (float)bp[3]);
    ((float4*)out)[b * MAXD + t] = bb;                              // det_bx
    out[B_IMG * MAXD * 4 + b * MAXD + t] = v;                       // det_sc
    out[B_IMG * MAXD * 5 + b * MAXD + t] = (float)(c + 1);          // det_lb (as float)
  }
}

extern "C" void kernel_launch(void* const* d_in, const int* in_sizes, int n_in,
                              void* d_out, int out_size, void* d_ws, size_t ws_size,
                              hipStream_t stream) {
  const float* cls_logits = (const float*)d_in[0];
  const float* bbox_pred  = (const float*)d_in[1];
  const float* priors     = (const float*)d_in[2];
  float* out = (float*)d_out;

  double* boxes   = (double*)d_ws;                                    // B*N*4 f64
  float* topk_sc  = (float*)(boxes + (size_t)B_IMG * N_PRI * 4);      // B*80*200 f32
  int*   topk_idx = (int*)(topk_sc + (size_t)B_IMG * N_FG * PRE);     // B*80*200 i32
  float* cls_sc   = (float*)(topk_idx + (size_t)B_IMG * N_FG * PRE);  // B*80*200 f32
  float* fgT      = cls_sc + (size_t)B_IMG * N_FG * PRE;              // chunkB*80*N f32

  size_t persist_bytes = (size_t)((char*)fgT - (char*)d_ws);
  size_t per_b = (size_t)N_FG * N_PRI * sizeof(float);
  int chunkB = 1;
  if (ws_size > persist_bytes) {
    size_t cb = (ws_size - persist_bytes) / per_b;
    chunkB = (cb >= (size_t)B_IMG) ? B_IMG : (cb < 1 ? 1 : (int)cb);
  }

  decode_kernel<<<dim3((N_PRI + 255) / 256, B_IMG), 256, 0, stream>>>(
      bbox_pred, priors, boxes);

  for (int b0 = 0; b0 < B_IMG; b0 += chunkB) {
    int nb = (B_IMG - b0) < chunkB ? (B_IMG - b0) : chunkB;
    softmax_fg_kernel<<<dim3((N_PRI + SMX_ROWS - 1) / SMX_ROWS, nb), 64, 0, stream>>>(
        cls_logits, fgT, b0);
    topk_kernel<<<dim3(N_FG, nb), 256, 0, stream>>>(
        fgT, topk_sc, topk_idx, b0);
  }

  nms_kernel<<<dim3(N_FG, B_IMG), 64, 0, stream>>>(
      topk_sc, topk_idx, boxes, cls_sc);

  final_kernel<<<B_IMG, 256, 0, stream>>>(
      cls_sc, topk_idx, boxes, out);
}